// Round 12
// baseline (220.715 us; speedup 1.0000x reference)
//
#include <hip/hip_runtime.h>

#define NPTS 32768
#define G 32
#define NCELL (G*G*G)          // 32768 cells per cloud
#define SSTR (NCELL + 1)
#define RANGE 4.5f
#define CELLW 0.28125f         // 9/32, exact in fp32

typedef unsigned int u32;

// Workspace layout:
//  [0K)     float4 sortedA[32768]   512KB   pred sorted; w = |t|^2/2
//  [512K)   float4 sortedB[32768]   512KB   targ sorted; w = |t|^2/2
//  [1024K)  u32    S[2][SSTR]       257KB   exclusive scan (+terminator NPTS)
//  [1344K)  u32    cnt[2][NCELL]    256KB   histogram; REUSED as straggler list
//  [1600K)  u32    cursor[2][NCELL] 256KB   scatter cursors
//  [1856K)  u32    strag_cnt        4B     (zeroed by hist_k each replay)

__device__ __forceinline__ int cell_of(float v) {
    int c = (int)floorf((v + RANGE) * (G / (2.0f * RANGE)));
    return min(max(c, 0), G - 1);   // outliers clamp inward -> all bounds stay conservative
}
__device__ __forceinline__ float cell_lo(int i) {   // exact: i*(9/32) - 4.5
    return fmaf((float)i, CELLW, -RANGE);
}

// ---- Build stage 1: histogram, one point/thread, global atomics ----
__global__ __launch_bounds__(256)
void hist_k(const float* __restrict__ pred, const float* __restrict__ targ,
            u32* __restrict__ cnt, u32* __restrict__ strag_cnt,
            float* __restrict__ out) {
    int i = blockIdx.x * 256 + threadIdx.x;          // 0..65535
    if (i == 0) { *out = 0.0f; *strag_cnt = 0u; }    // re-zeroed every replay
    int cloud = i >> 15, k = i & (NPTS - 1);
    const float* p = cloud ? targ : pred;
    float x = p[3*k], y = p[3*k+1], z = p[3*k+2];
    int c = (cell_of(z) * G + cell_of(y)) * G + cell_of(x);
    atomicAdd(&cnt[cloud * NCELL + c], 1u);
}

// ---- Build stage 2: per-cloud exclusive scan (1 block/cloud, 32 cells/thread) ----
__global__ __launch_bounds__(1024)
void scan_k(const u32* __restrict__ cnt, u32* __restrict__ S, u32* __restrict__ cursor) {
    int cloud = blockIdx.x;
    const u32* c = cnt + cloud * NCELL;
    u32* s   = S + cloud * SSTR;
    u32* cur = cursor + cloud * NCELL;
    __shared__ u32 wt[16];
    int t = threadIdx.x, lane = t & 63, wave = t >> 6;

    u32 loc[32], run = 0;
    #pragma unroll
    for (int k = 0; k < 32; ++k) { loc[k] = run; run += c[32 * t + k]; }
    u32 inc = run;
    #pragma unroll
    for (int off = 1; off < 64; off <<= 1) {
        u32 nv = __shfl_up(inc, off, 64);
        if (lane >= off) inc += nv;
    }
    if (lane == 63) wt[wave] = inc;
    __syncthreads();
    if (t == 0) {
        u32 a = 0;
        #pragma unroll
        for (int w = 0; w < 16; ++w) { u32 v = wt[w]; wt[w] = a; a += v; }
    }
    __syncthreads();
    u32 tb = wt[wave] + (inc - run);                 // exclusive base for cell 32t
    #pragma unroll
    for (int k = 0; k < 32; ++k) {
        u32 v = tb + loc[k];
        s[32 * t + k] = v; cur[32 * t + k] = v;
    }
    if (t == 1023) s[NCELL] = NPTS;
}

// ---- Build stage 3: scatter; w = |t|^2/2 for the h-form distance ----
__global__ __launch_bounds__(256)
void scatter_k(const float* __restrict__ pred, const float* __restrict__ targ,
               u32* __restrict__ cursor,
               float4* __restrict__ sortedA, float4* __restrict__ sortedB) {
    int i = blockIdx.x * 256 + threadIdx.x;
    int cloud = i >> 15, k = i & (NPTS - 1);
    const float* p = cloud ? targ : pred;
    float x = p[3*k], y = p[3*k+1], z = p[3*k+2];
    int c = (cell_of(z) * G + cell_of(y)) * G + cell_of(x);
    u32 pos = atomicAdd(&cursor[cloud * NCELL + c], 1u);
    (cloud ? sortedB : sortedA)[pos] =
        make_float4(x, y, z, 0.5f * fmaf(x, x, fmaf(y, y, z * z)));
}

// distance from q to the boundary of box(R); domain-edge faces skipped
// (points clamp inward -> nothing lies beyond them): bound stays conservative.
__device__ __forceinline__ float box_bound(int cx, int cy, int cz, float4 q, int R) {
    float bd = 3.4e38f;
    if (cx - R > 0)     bd = fminf(bd, q.x - cell_lo(cx - R));
    if (cx + R < G - 1) bd = fminf(bd, cell_lo(cx + R + 1) - q.x);
    if (cy - R > 0)     bd = fminf(bd, q.y - cell_lo(cy - R));
    if (cy + R < G - 1) bd = fminf(bd, cell_lo(cy + R + 1) - q.y);
    if (cz - R > 0)     bd = fminf(bd, q.z - cell_lo(cz - R));
    if (cz + R < G - 1) bd = fminf(bd, cell_lo(cz + R + 1) - q.z);
    return bd;
}

// ---- Phase 1: dense path. 8 lanes/query, clustered (wave-coherent).
// h-form: h(t) = |t|^2/2 - q.t  (t.w pre-holds |t|^2/2);  d^2 = |q|^2 + 2*h_min.
// scan loop unrolled x4: 4 independent named loads in flight, clamped indices +
// cndmask INF masking (branchless tail). 27-box in 2 latency rounds; groups
// whose box bound fails go to the straggler list and contribute 0 here.
__global__ __launch_bounds__(256, 8)
void query_dense(const float4* __restrict__ sortedA, const float4* __restrict__ sortedB,
                 const u32* __restrict__ Sall, u32* __restrict__ strag_cnt,
                 u32* __restrict__ strag_list, float* __restrict__ out) {
    int tid = blockIdx.x * 256 + threadIdx.x;        // 0..524287
    int sub = tid & 7;
    int qi = tid >> 3;                               // clustered: wave = 8 adjacent queries
    int cloud = qi >> 15, k = qi & (NPTS - 1);
    const float4* Q = cloud ? sortedB : sortedA;
    const float4* T = cloud ? sortedA : sortedB;
    const u32* s = Sall + (cloud ^ 1) * SSTR;        // other cloud's grid

    float4 q = Q[k];                                 // q.w = |q|^2/2
    int cx = cell_of(q.x), cy = cell_of(q.y), cz = cell_of(q.z);
    int x0 = max(cx - 1, 0), x1 = min(cx + 1, G - 1);
    float hb = 3.4e38f;                              // running min of h

    // center-row + 8 neighbor-row descriptors: issued early, all independent
    int cbc = (cz * G + cy) * G;
    u32 cbeg = s[cbc + x0], cend = s[cbc + x1 + 1];
    u32 rb[9], re[9];
    #pragma unroll
    for (int i = 0; i < 9; ++i) {
        int dy = (i % 3) - 1, dz = (i / 3) - 1;
        int Y = cy + dy, Z = cz + dz;
        rb[i] = 0; re[i] = 0;
        if (i != 4 && (unsigned)Y < G && (unsigned)Z < G) {
            int cb = (Z * G + Y) * G;
            rb[i] = s[cb + x0]; re[i] = s[cb + x1 + 1];
        }
    }

    auto hval = [&](float4 t) {                      // 3 fma
        return fmaf(-q.x, t.x, fmaf(-q.y, t.y, fmaf(-q.z, t.z, t.w)));
    };
    auto scan_seg = [&](u32 beg, u32 end) {
        for (u32 e = beg + sub; e < end; e += 32) {  // x4 unroll, 4 loads in flight
            u32 e1 = min(e + 8u,  (u32)NPTS - 1);
            u32 e2 = min(e + 16u, (u32)NPTS - 1);
            u32 e3 = min(e + 24u, (u32)NPTS - 1);
            float4 t0 = T[e];  float4 t1 = T[e1];
            float4 t2 = T[e2]; float4 t3 = T[e3];
            float h0 = hval(t0);
            float h1 = (e + 8u  < end) ? hval(t1) : 3.4e38f;
            float h2 = (e + 16u < end) ? hval(t2) : 3.4e38f;
            float h3 = (e + 24u < end) ? hval(t3) : 3.4e38f;
            hb = fminf(hb, fminf(fminf(h0, h1), fminf(h2, h3)));
        }
    };
    auto group_min = [&]() {
        hb = fminf(hb, __shfl_xor(hb, 1, 64));
        hb = fminf(hb, __shfl_xor(hb, 2, 64));
        hb = fminf(hb, __shfl_xor(hb, 4, 64));
    };

    // round 1: center row (contains own cell)
    scan_seg(cbeg, cend);
    group_min();

    // round 2: prune rows against post-center best, scan survivors.
    // d^2-space: mind2 < best_d2  <=>  0.5*mind2 - q.w < hb. Exact skip.
    #pragma unroll
    for (int i = 0; i < 9; ++i) {
        if (i == 4) continue;
        int dy = (i % 3) - 1, dz = (i / 3) - 1;
        int Y = cy + dy, Z = cz + dz;
        if ((unsigned)Y >= G || (unsigned)Z >= G) continue;
        float ey = dy > 0 ? cell_lo(Y) - q.y : q.y - cell_lo(Y + 1);
        float ez = dz > 0 ? cell_lo(Z) - q.z : q.z - cell_lo(Z + 1);
        if (dy == 0) ey = 0.0f;
        if (dz == 0) ez = 0.0f;
        float mind2 = fmaf(ey, ey, ez * ez);
        if (fmaf(0.5f, mind2, -q.w) < hb) scan_seg(rb[i], re[i]);
    }
    group_min();                                     // hb now group-uniform

    // straggler handoff: best_d2 > bd^2  <=>  hb > 0.5*bd^2 - q.w
    float bd = box_bound(cx, cy, cz, q, 1);
    float best;                                      // d^2 contribution
    if (hb > fmaf(0.5f * bd, bd, -q.w)) {
        if (sub == 0) {
            u32 slot = atomicAdd(strag_cnt, 1u);
            strag_list[slot] = (u32)qi;
        }
        best = 0.0f;                                 // phase 2 contributes the real value
    } else {
        best = fmaxf(fmaf(2.0f, hb, 2.0f * q.w), 0.0f);
    }

    // fused mean: each query's best replicated on its 8 lanes -> weight 1/8
    float v = best * 0.125f;
    #pragma unroll
    for (int off = 1; off < 64; off <<= 1)
        v += __shfl_xor(v, off, 64);
    __shared__ float wsum[4];
    int lane = threadIdx.x & 63, wave = threadIdx.x >> 6;
    if (lane == 0) wsum[wave] = v;
    __syncthreads();
    if (threadIdx.x == 0)
        atomicAdd(out, (wsum[0] + wsum[1] + wsum[2] + wsum[3]) * (1.0f / NPTS));
}

// ---- Phase 2: one 64-lane wave per straggler (grid-stride over the list).
// ---- box(4) with per-lane row ownership (one descriptor latency round), then
// ---- whole-cloud brute ONLY if best > bd4^2: 8-wide batched named loads +
// ---- 4 accumulators (proven: removed strag from the top-5 in R11).
__global__ __launch_bounds__(256, 8)
void query_strag(const float4* __restrict__ sortedA, const float4* __restrict__ sortedB,
                 const u32* __restrict__ Sall, const u32* __restrict__ strag_cnt,
                 const u32* __restrict__ strag_list, float* __restrict__ out) {
    u32 n = *strag_cnt;
    int lane = threadIdx.x & 63;
    u32 wid = (blockIdx.x * 256 + threadIdx.x) >> 6;
    u32 nw = (gridDim.x * 256) >> 6;

    for (u32 idx = wid; idx < n; idx += nw) {
        u32 qi = strag_list[idx];
        int cloud = qi >> 15, k = qi & (NPTS - 1);
        const float4* Q = cloud ? sortedB : sortedA;
        const float4* T = cloud ? sortedA : sortedB;
        const u32* s = Sall + (cloud ^ 1) * SSTR;

        float4 q = Q[k];
        int cx = cell_of(q.x), cy = cell_of(q.y), cz = cell_of(q.z);
        int xlo = max(cx - 4, 0), xhi = min(cx + 4, G - 1);
        float best = 3.4e38f;

        // lane-owned rows of the 9x9 (dy,dz) sheet: ri = lane and lane+64
        u32 rb0 = 0, re0 = 0, rb1 = 0, re1 = 0;
        {
            int Z = cz + lane / 9 - 4, Y = cy + lane % 9 - 4;
            if ((unsigned)Z < G && (unsigned)Y < G) {
                int cb = (Z * G + Y) * G;
                rb0 = s[cb + xlo]; re0 = s[cb + xhi + 1];
            }
        }
        if (lane < 17) {
            int ri = lane + 64;
            int Z = cz + ri / 9 - 4, Y = cy + ri % 9 - 4;
            if ((unsigned)Z < G && (unsigned)Y < G) {
                int cb = (Z * G + Y) * G;
                rb1 = s[cb + xlo]; re1 = s[cb + xhi + 1];
            }
        }
        for (u32 e = rb0; e < re0; ++e) {
            float4 t = T[e];
            float dx = q.x - t.x, dy = q.y - t.y, dz = q.z - t.z;
            best = fminf(best, fmaf(dx, dx, fmaf(dy, dy, dz * dz)));
        }
        for (u32 e = rb1; e < re1; ++e) {
            float4 t = T[e];
            float dx = q.x - t.x, dy = q.y - t.y, dz = q.z - t.z;
            best = fminf(best, fmaf(dx, dx, fmaf(dy, dy, dz * dz)));
        }
        #pragma unroll
        for (int off = 1; off < 64; off <<= 1)
            best = fminf(best, __shfl_xor(best, off, 64));

        float bd4 = box_bound(cx, cy, cz, q, 4);     // >= ~1.27 in-domain
        if (best > bd4 * bd4) {
            auto d2 = [&](float4 t) {
                float dx = q.x - t.x, dy = q.y - t.y, dz = q.z - t.z;
                return fmaf(dx, dx, fmaf(dy, dy, dz * dz));
            };
            float a0 = 3.4e38f, a1 = 3.4e38f, a2 = 3.4e38f, a3 = 3.4e38f;
            #pragma unroll 2
            for (int blk = 0; blk < NPTS / 512; ++blk) {
                u32 base = (u32)lane + (u32)blk * 512u;
                float4 t0 = T[base];       float4 t1 = T[base + 64];
                float4 t2 = T[base + 128]; float4 t3 = T[base + 192];
                float4 t4 = T[base + 256]; float4 t5 = T[base + 320];
                float4 t6 = T[base + 384]; float4 t7 = T[base + 448];
                a0 = fminf(a0, d2(t0)); a1 = fminf(a1, d2(t1));
                a2 = fminf(a2, d2(t2)); a3 = fminf(a3, d2(t3));
                a0 = fminf(a0, d2(t4)); a1 = fminf(a1, d2(t5));
                a2 = fminf(a2, d2(t6)); a3 = fminf(a3, d2(t7));
            }
            float bb = fminf(fminf(a0, a1), fminf(a2, a3));
            #pragma unroll
            for (int off = 1; off < 64; off <<= 1)
                bb = fminf(bb, __shfl_xor(bb, off, 64));
            best = fminf(best, bb);
        }

        if (lane == 0) atomicAdd(out, best * (1.0f / NPTS));
    }
}

extern "C" void kernel_launch(void* const* d_in, const int* in_sizes, int n_in,
                              void* d_out, int out_size, void* d_ws, size_t ws_size,
                              hipStream_t stream) {
    const float* pred = (const float*)d_in[0];
    const float* targ = (const float*)d_in[1];
    float* out = (float*)d_out;
    char* ws = (char*)d_ws;
    float4* sortedA = (float4*)(ws);
    float4* sortedB = (float4*)(ws + (512 << 10));
    u32* S         = (u32*)(ws + (1024 << 10));
    u32* cnt       = (u32*)(ws + (1344 << 10));   // dead after scan_k
    u32* cursor    = (u32*)(ws + (1600 << 10));
    u32* strag_cnt = (u32*)(ws + (1856 << 10));
    u32* strag_list = cnt;                        // reuse: list written after scan_k

    hipMemsetAsync(cnt, 0, 2 * NCELL * sizeof(u32), stream);
    hist_k     <<<256, 256, 0, stream>>>(pred, targ, cnt, strag_cnt, out);
    scan_k     <<<2, 1024, 0, stream>>>(cnt, S, cursor);
    scatter_k  <<<256, 256, 0, stream>>>(pred, targ, cursor, sortedA, sortedB);
    query_dense<<<2048, 256, 0, stream>>>(sortedA, sortedB, S, strag_cnt, strag_list, out);
    query_strag<<<512, 256, 0, stream>>>(sortedA, sortedB, S, strag_cnt, strag_list, out);
}

// Round 13
// 206.331 us; speedup vs baseline: 1.0697x; 1.0697x over previous
//
#include <hip/hip_runtime.h>

#define NPTS 32768
#define G 32
#define NCELL (G*G*G)          // 32768 cells per cloud
#define SSTR (NCELL + 1)
#define RANGE 4.5f
#define CELLW 0.28125f         // 9/32, exact in fp32

typedef unsigned int u32;

// Workspace layout:
//  [0K)     float4 sortedA[32768]   512KB   pred sorted; w = |t|^2/2
//  [512K)   float4 sortedB[32768]   512KB   targ sorted; w = |t|^2/2
//  [1024K)  u32    S[2][SSTR]       257KB   exclusive scan (+terminator NPTS)
//  [1344K)  u32    cnt[2][NCELL]    256KB   histogram; REUSED as straggler list
//  [1600K)  u32    cursor[2][NCELL] 256KB   scatter cursors
//  [1856K)  u32    strag_cnt        4B     (zeroed by hist_k each replay)

__device__ __forceinline__ int cell_of(float v) {
    int c = (int)floorf((v + RANGE) * (G / (2.0f * RANGE)));
    return min(max(c, 0), G - 1);   // outliers clamp inward -> all bounds stay conservative
}
__device__ __forceinline__ float cell_lo(int i) {   // exact: i*(9/32) - 4.5
    return fmaf((float)i, CELLW, -RANGE);
}

// ---- Build stage 1: histogram, one point/thread, global atomics ----
__global__ __launch_bounds__(256)
void hist_k(const float* __restrict__ pred, const float* __restrict__ targ,
            u32* __restrict__ cnt, u32* __restrict__ strag_cnt,
            float* __restrict__ out) {
    int i = blockIdx.x * 256 + threadIdx.x;          // 0..65535
    if (i == 0) { *out = 0.0f; *strag_cnt = 0u; }    // re-zeroed every replay
    int cloud = i >> 15, k = i & (NPTS - 1);
    const float* p = cloud ? targ : pred;
    float x = p[3*k], y = p[3*k+1], z = p[3*k+2];
    int c = (cell_of(z) * G + cell_of(y)) * G + cell_of(x);
    atomicAdd(&cnt[cloud * NCELL + c], 1u);
}

// ---- Build stage 2: per-cloud exclusive scan (1 block/cloud, 32 cells/thread) ----
__global__ __launch_bounds__(1024)
void scan_k(const u32* __restrict__ cnt, u32* __restrict__ S, u32* __restrict__ cursor) {
    int cloud = blockIdx.x;
    const u32* c = cnt + cloud * NCELL;
    u32* s   = S + cloud * SSTR;
    u32* cur = cursor + cloud * NCELL;
    __shared__ u32 wt[16];
    int t = threadIdx.x, lane = t & 63, wave = t >> 6;

    u32 loc[32], run = 0;
    #pragma unroll
    for (int k = 0; k < 32; ++k) { loc[k] = run; run += c[32 * t + k]; }
    u32 inc = run;
    #pragma unroll
    for (int off = 1; off < 64; off <<= 1) {
        u32 nv = __shfl_up(inc, off, 64);
        if (lane >= off) inc += nv;
    }
    if (lane == 63) wt[wave] = inc;
    __syncthreads();
    if (t == 0) {
        u32 a = 0;
        #pragma unroll
        for (int w = 0; w < 16; ++w) { u32 v = wt[w]; wt[w] = a; a += v; }
    }
    __syncthreads();
    u32 tb = wt[wave] + (inc - run);                 // exclusive base for cell 32t
    #pragma unroll
    for (int k = 0; k < 32; ++k) {
        u32 v = tb + loc[k];
        s[32 * t + k] = v; cur[32 * t + k] = v;
    }
    if (t == 1023) s[NCELL] = NPTS;
}

// ---- Build stage 3: scatter; w = |t|^2/2 for the h-form distance ----
__global__ __launch_bounds__(256)
void scatter_k(const float* __restrict__ pred, const float* __restrict__ targ,
               u32* __restrict__ cursor,
               float4* __restrict__ sortedA, float4* __restrict__ sortedB) {
    int i = blockIdx.x * 256 + threadIdx.x;
    int cloud = i >> 15, k = i & (NPTS - 1);
    const float* p = cloud ? targ : pred;
    float x = p[3*k], y = p[3*k+1], z = p[3*k+2];
    int c = (cell_of(z) * G + cell_of(y)) * G + cell_of(x);
    u32 pos = atomicAdd(&cursor[cloud * NCELL + c], 1u);
    (cloud ? sortedB : sortedA)[pos] =
        make_float4(x, y, z, 0.5f * fmaf(x, x, fmaf(y, y, z * z)));
}

// distance from q to the boundary of box(R); domain-edge faces skipped
// (points clamp inward -> nothing lies beyond them): bound stays conservative.
__device__ __forceinline__ float box_bound(int cx, int cy, int cz, float4 q, int R) {
    float bd = 3.4e38f;
    if (cx - R > 0)     bd = fminf(bd, q.x - cell_lo(cx - R));
    if (cx + R < G - 1) bd = fminf(bd, cell_lo(cx + R + 1) - q.x);
    if (cy - R > 0)     bd = fminf(bd, q.y - cell_lo(cy - R));
    if (cy + R < G - 1) bd = fminf(bd, cell_lo(cy + R + 1) - q.y);
    if (cz - R > 0)     bd = fminf(bd, q.z - cell_lo(cz - R));
    if (cz + R < G - 1) bd = fminf(bd, cell_lo(cz + R + 1) - q.z);
    return bd;
}

// ---- Phase 1: dense path. 8 lanes/query, clustered (wave-coherent).
// h-form: h(t) = |t|^2/2 - q.t (t.w holds |t|^2/2); d^2 = 2*hb + 2*q.w.
// scan loop unrolled x2 (NOT x4: R12's x4 spilled to scratch under the
// 64-VGPR cap of launch_bounds(256,8) -> 322MB scratch writes, 2.5x slower).
// 2 independent named loads in flight, clamped idx + INF-masked tail.
__global__ __launch_bounds__(256, 8)
void query_dense(const float4* __restrict__ sortedA, const float4* __restrict__ sortedB,
                 const u32* __restrict__ Sall, u32* __restrict__ strag_cnt,
                 u32* __restrict__ strag_list, float* __restrict__ out) {
    int tid = blockIdx.x * 256 + threadIdx.x;        // 0..524287
    int sub = tid & 7;
    int qi = tid >> 3;                               // clustered: wave = 8 adjacent queries
    int cloud = qi >> 15, k = qi & (NPTS - 1);
    const float4* Q = cloud ? sortedB : sortedA;
    const float4* T = cloud ? sortedA : sortedB;
    const u32* s = Sall + (cloud ^ 1) * SSTR;        // other cloud's grid

    float4 q = Q[k];                                 // q.w = |q|^2/2
    int cx = cell_of(q.x), cy = cell_of(q.y), cz = cell_of(q.z);
    int x0 = max(cx - 1, 0), x1 = min(cx + 1, G - 1);
    float hb = 3.4e38f;                              // running min of h

    // center-row + 8 neighbor-row descriptors: issued early, all independent
    int cbc = (cz * G + cy) * G;
    u32 cbeg = s[cbc + x0], cend = s[cbc + x1 + 1];
    u32 rb[9], re[9];
    #pragma unroll
    for (int i = 0; i < 9; ++i) {
        int dy = (i % 3) - 1, dz = (i / 3) - 1;
        int Y = cy + dy, Z = cz + dz;
        rb[i] = 0; re[i] = 0;
        if (i != 4 && (unsigned)Y < G && (unsigned)Z < G) {
            int cb = (Z * G + Y) * G;
            rb[i] = s[cb + x0]; re[i] = s[cb + x1 + 1];
        }
    }

    auto hval = [&](float4 t) {                      // 3 fma
        return fmaf(-q.x, t.x, fmaf(-q.y, t.y, fmaf(-q.z, t.z, t.w)));
    };
    auto scan_seg = [&](u32 beg, u32 end) {
        for (u32 e = beg + sub; e < end; e += 16) {  // x2 unroll, 2 loads in flight
            u32 e1 = min(e + 8u, (u32)NPTS - 1);
            float4 t0 = T[e];
            float4 t1 = T[e1];
            float h0 = hval(t0);
            float h1 = (e + 8u < end) ? hval(t1) : 3.4e38f;
            hb = fminf(hb, fminf(h0, h1));
        }
    };
    auto group_min = [&]() {
        hb = fminf(hb, __shfl_xor(hb, 1, 64));
        hb = fminf(hb, __shfl_xor(hb, 2, 64));
        hb = fminf(hb, __shfl_xor(hb, 4, 64));
    };

    // round 1: center row (contains own cell)
    scan_seg(cbeg, cend);
    group_min();

    // round 2: prune rows against post-center best, scan survivors.
    // d^2-space: mind2 < best_d2  <=>  0.5*mind2 - q.w < hb. Exact skip.
    #pragma unroll
    for (int i = 0; i < 9; ++i) {
        if (i == 4) continue;
        int dy = (i % 3) - 1, dz = (i / 3) - 1;
        int Y = cy + dy, Z = cz + dz;
        if ((unsigned)Y >= G || (unsigned)Z >= G) continue;
        float ey = dy > 0 ? cell_lo(Y) - q.y : q.y - cell_lo(Y + 1);
        float ez = dz > 0 ? cell_lo(Z) - q.z : q.z - cell_lo(Z + 1);
        if (dy == 0) ey = 0.0f;
        if (dz == 0) ez = 0.0f;
        float mind2 = fmaf(ey, ey, ez * ez);
        if (fmaf(0.5f, mind2, -q.w) < hb) scan_seg(rb[i], re[i]);
    }
    group_min();                                     // hb now group-uniform

    // straggler handoff: best_d2 > bd^2  <=>  hb > 0.5*bd^2 - q.w
    float bd = box_bound(cx, cy, cz, q, 1);
    float best;                                      // d^2 contribution
    if (hb > fmaf(0.5f * bd, bd, -q.w)) {
        if (sub == 0) {
            u32 slot = atomicAdd(strag_cnt, 1u);
            strag_list[slot] = (u32)qi;
        }
        best = 0.0f;                                 // phase 2 contributes the real value
    } else {
        best = fmaxf(fmaf(2.0f, hb, 2.0f * q.w), 0.0f);
    }

    // fused mean: each query's best replicated on its 8 lanes -> weight 1/8
    float v = best * 0.125f;
    #pragma unroll
    for (int off = 1; off < 64; off <<= 1)
        v += __shfl_xor(v, off, 64);
    __shared__ float wsum[4];
    int lane = threadIdx.x & 63, wave = threadIdx.x >> 6;
    if (lane == 0) wsum[wave] = v;
    __syncthreads();
    if (threadIdx.x == 0)
        atomicAdd(out, (wsum[0] + wsum[1] + wsum[2] + wsum[3]) * (1.0f / NPTS));
}

// ---- Phase 2: one 64-lane wave per straggler (grid-stride over the list).
// ---- box(4) with per-lane row ownership (one descriptor latency round), then
// ---- whole-cloud brute ONLY if best > bd4^2: 8-wide batched named loads +
// ---- 4 accumulators (proven: removed strag from the top-5 in R11).
__global__ __launch_bounds__(256, 8)
void query_strag(const float4* __restrict__ sortedA, const float4* __restrict__ sortedB,
                 const u32* __restrict__ Sall, const u32* __restrict__ strag_cnt,
                 const u32* __restrict__ strag_list, float* __restrict__ out) {
    u32 n = *strag_cnt;
    int lane = threadIdx.x & 63;
    u32 wid = (blockIdx.x * 256 + threadIdx.x) >> 6;
    u32 nw = (gridDim.x * 256) >> 6;

    for (u32 idx = wid; idx < n; idx += nw) {
        u32 qi = strag_list[idx];
        int cloud = qi >> 15, k = qi & (NPTS - 1);
        const float4* Q = cloud ? sortedB : sortedA;
        const float4* T = cloud ? sortedA : sortedB;
        const u32* s = Sall + (cloud ^ 1) * SSTR;

        float4 q = Q[k];
        int cx = cell_of(q.x), cy = cell_of(q.y), cz = cell_of(q.z);
        int xlo = max(cx - 4, 0), xhi = min(cx + 4, G - 1);
        float best = 3.4e38f;

        // lane-owned rows of the 9x9 (dy,dz) sheet: ri = lane and lane+64
        u32 rb0 = 0, re0 = 0, rb1 = 0, re1 = 0;
        {
            int Z = cz + lane / 9 - 4, Y = cy + lane % 9 - 4;
            if ((unsigned)Z < G && (unsigned)Y < G) {
                int cb = (Z * G + Y) * G;
                rb0 = s[cb + xlo]; re0 = s[cb + xhi + 1];
            }
        }
        if (lane < 17) {
            int ri = lane + 64;
            int Z = cz + ri / 9 - 4, Y = cy + ri % 9 - 4;
            if ((unsigned)Z < G && (unsigned)Y < G) {
                int cb = (Z * G + Y) * G;
                rb1 = s[cb + xlo]; re1 = s[cb + xhi + 1];
            }
        }
        for (u32 e = rb0; e < re0; ++e) {
            float4 t = T[e];
            float dx = q.x - t.x, dy = q.y - t.y, dz = q.z - t.z;
            best = fminf(best, fmaf(dx, dx, fmaf(dy, dy, dz * dz)));
        }
        for (u32 e = rb1; e < re1; ++e) {
            float4 t = T[e];
            float dx = q.x - t.x, dy = q.y - t.y, dz = q.z - t.z;
            best = fminf(best, fmaf(dx, dx, fmaf(dy, dy, dz * dz)));
        }
        #pragma unroll
        for (int off = 1; off < 64; off <<= 1)
            best = fminf(best, __shfl_xor(best, off, 64));

        float bd4 = box_bound(cx, cy, cz, q, 4);     // >= ~1.27 in-domain
        if (best > bd4 * bd4) {
            auto d2 = [&](float4 t) {
                float dx = q.x - t.x, dy = q.y - t.y, dz = q.z - t.z;
                return fmaf(dx, dx, fmaf(dy, dy, dz * dz));
            };
            float a0 = 3.4e38f, a1 = 3.4e38f, a2 = 3.4e38f, a3 = 3.4e38f;
            #pragma unroll 2
            for (int blk = 0; blk < NPTS / 512; ++blk) {
                u32 base = (u32)lane + (u32)blk * 512u;
                float4 t0 = T[base];       float4 t1 = T[base + 64];
                float4 t2 = T[base + 128]; float4 t3 = T[base + 192];
                float4 t4 = T[base + 256]; float4 t5 = T[base + 320];
                float4 t6 = T[base + 384]; float4 t7 = T[base + 448];
                a0 = fminf(a0, d2(t0)); a1 = fminf(a1, d2(t1));
                a2 = fminf(a2, d2(t2)); a3 = fminf(a3, d2(t3));
                a0 = fminf(a0, d2(t4)); a1 = fminf(a1, d2(t5));
                a2 = fminf(a2, d2(t6)); a3 = fminf(a3, d2(t7));
            }
            float bb = fminf(fminf(a0, a1), fminf(a2, a3));
            #pragma unroll
            for (int off = 1; off < 64; off <<= 1)
                bb = fminf(bb, __shfl_xor(bb, off, 64));
            best = fminf(best, bb);
        }

        if (lane == 0) atomicAdd(out, best * (1.0f / NPTS));
    }
}

extern "C" void kernel_launch(void* const* d_in, const int* in_sizes, int n_in,
                              void* d_out, int out_size, void* d_ws, size_t ws_size,
                              hipStream_t stream) {
    const float* pred = (const float*)d_in[0];
    const float* targ = (const float*)d_in[1];
    float* out = (float*)d_out;
    char* ws = (char*)d_ws;
    float4* sortedA = (float4*)(ws);
    float4* sortedB = (float4*)(ws + (512 << 10));
    u32* S         = (u32*)(ws + (1024 << 10));
    u32* cnt       = (u32*)(ws + (1344 << 10));   // dead after scan_k
    u32* cursor    = (u32*)(ws + (1600 << 10));
    u32* strag_cnt = (u32*)(ws + (1856 << 10));
    u32* strag_list = cnt;                        // reuse: list written after scan_k

    hipMemsetAsync(cnt, 0, 2 * NCELL * sizeof(u32), stream);
    hist_k     <<<256, 256, 0, stream>>>(pred, targ, cnt, strag_cnt, out);
    scan_k     <<<2, 1024, 0, stream>>>(cnt, S, cursor);
    scatter_k  <<<256, 256, 0, stream>>>(pred, targ, cursor, sortedA, sortedB);
    query_dense<<<2048, 256, 0, stream>>>(sortedA, sortedB, S, strag_cnt, strag_list, out);
    query_strag<<<512, 256, 0, stream>>>(sortedA, sortedB, S, strag_cnt, strag_list, out);
}

// Round 14
// 177.816 us; speedup vs baseline: 1.2413x; 1.1604x over previous
//
#include <hip/hip_runtime.h>

#define NPTS 32768
#define G 32
#define NCELL (G*G*G)          // 32768 cells per cloud
#define SSTR (NCELL + 1)
#define RANGE 4.5f
#define CELLW 0.28125f         // 9/32, exact in fp32

typedef unsigned int u32;

// Workspace layout:
//  [0K)     float4 sortedA[32768]   512KB   pred sorted; w = |t|^2/2
//  [512K)   float4 sortedB[32768]   512KB   targ sorted; w = |t|^2/2
//  [1024K)  u32    S[2][SSTR]       257KB   exclusive scan (+terminator NPTS)
//  [1344K)  u32    cnt[2][NCELL]    256KB   histogram; REUSED as straggler list
//  [1600K)  u32    cursor[2][NCELL] 256KB   scatter cursors
//  [1856K)  u32    strag_cnt        4B     (zeroed by hist_k each replay)

__device__ __forceinline__ int cell_of(float v) {
    int c = (int)floorf((v + RANGE) * (G / (2.0f * RANGE)));
    return min(max(c, 0), G - 1);   // outliers clamp inward -> all bounds stay conservative
}
__device__ __forceinline__ float cell_lo(int i) {   // exact: i*(9/32) - 4.5
    return fmaf((float)i, CELLW, -RANGE);
}

// ---- Build stage 1: histogram, one point/thread, global atomics ----
__global__ __launch_bounds__(256)
void hist_k(const float* __restrict__ pred, const float* __restrict__ targ,
            u32* __restrict__ cnt, u32* __restrict__ strag_cnt,
            float* __restrict__ out) {
    int i = blockIdx.x * 256 + threadIdx.x;          // 0..65535
    if (i == 0) { *out = 0.0f; *strag_cnt = 0u; }    // re-zeroed every replay
    int cloud = i >> 15, k = i & (NPTS - 1);
    const float* p = cloud ? targ : pred;
    float x = p[3*k], y = p[3*k+1], z = p[3*k+2];
    int c = (cell_of(z) * G + cell_of(y)) * G + cell_of(x);
    atomicAdd(&cnt[cloud * NCELL + c], 1u);
}

// ---- Build stage 2: per-cloud exclusive scan (1 block/cloud, 32 cells/thread) ----
__global__ __launch_bounds__(1024)
void scan_k(const u32* __restrict__ cnt, u32* __restrict__ S, u32* __restrict__ cursor) {
    int cloud = blockIdx.x;
    const u32* c = cnt + cloud * NCELL;
    u32* s   = S + cloud * SSTR;
    u32* cur = cursor + cloud * NCELL;
    __shared__ u32 wt[16];
    int t = threadIdx.x, lane = t & 63, wave = t >> 6;

    u32 loc[32], run = 0;
    #pragma unroll
    for (int k = 0; k < 32; ++k) { loc[k] = run; run += c[32 * t + k]; }
    u32 inc = run;
    #pragma unroll
    for (int off = 1; off < 64; off <<= 1) {
        u32 nv = __shfl_up(inc, off, 64);
        if (lane >= off) inc += nv;
    }
    if (lane == 63) wt[wave] = inc;
    __syncthreads();
    if (t == 0) {
        u32 a = 0;
        #pragma unroll
        for (int w = 0; w < 16; ++w) { u32 v = wt[w]; wt[w] = a; a += v; }
    }
    __syncthreads();
    u32 tb = wt[wave] + (inc - run);                 // exclusive base for cell 32t
    #pragma unroll
    for (int k = 0; k < 32; ++k) {
        u32 v = tb + loc[k];
        s[32 * t + k] = v; cur[32 * t + k] = v;
    }
    if (t == 1023) s[NCELL] = NPTS;
}

// ---- Build stage 3: scatter; w = |t|^2/2 for the h-form distance ----
__global__ __launch_bounds__(256)
void scatter_k(const float* __restrict__ pred, const float* __restrict__ targ,
               u32* __restrict__ cursor,
               float4* __restrict__ sortedA, float4* __restrict__ sortedB) {
    int i = blockIdx.x * 256 + threadIdx.x;
    int cloud = i >> 15, k = i & (NPTS - 1);
    const float* p = cloud ? targ : pred;
    float x = p[3*k], y = p[3*k+1], z = p[3*k+2];
    int c = (cell_of(z) * G + cell_of(y)) * G + cell_of(x);
    u32 pos = atomicAdd(&cursor[cloud * NCELL + c], 1u);
    (cloud ? sortedB : sortedA)[pos] =
        make_float4(x, y, z, 0.5f * fmaf(x, x, fmaf(y, y, z * z)));
}

// distance from q to the boundary of box(R); domain-edge faces skipped
// (points clamp inward -> nothing lies beyond them): bound stays conservative.
__device__ __forceinline__ float box_bound(int cx, int cy, int cz, float4 q, int R) {
    float bd = 3.4e38f;
    if (cx - R > 0)     bd = fminf(bd, q.x - cell_lo(cx - R));
    if (cx + R < G - 1) bd = fminf(bd, cell_lo(cx + R + 1) - q.x);
    if (cy - R > 0)     bd = fminf(bd, q.y - cell_lo(cy - R));
    if (cy + R < G - 1) bd = fminf(bd, cell_lo(cy + R + 1) - q.y);
    if (cz - R > 0)     bd = fminf(bd, q.z - cell_lo(cz - R));
    if (cz + R < G - 1) bd = fminf(bd, cell_lo(cz + R + 1) - q.z);
    return bd;
}

// ---- Phase 1: dense path. 8 lanes/query, clustered (wave-coherent).
// h-form: h(t) = |t|^2/2 - q.t (t.w holds |t|^2/2); d^2 = 2*hb + 2*q.w.
// scan x4-unrolled: 4 independent named loads in flight. launch_bounds(256,4)
// gives a 128-VGPR cap -- R12/R13 proved the x4/x2 live set spills under the
// 64-VGPR cap of (256,8) (WRITE_SIZE 322MB/199MB scratch signature). MLP:
// 4 waves/SIMD x 4-deep = 16 outstanding loads vs R11's 8x1 = 8.
__global__ __launch_bounds__(256, 4)
void query_dense(const float4* __restrict__ sortedA, const float4* __restrict__ sortedB,
                 const u32* __restrict__ Sall, u32* __restrict__ strag_cnt,
                 u32* __restrict__ strag_list, float* __restrict__ out) {
    int tid = blockIdx.x * 256 + threadIdx.x;        // 0..524287
    int sub = tid & 7;
    int qi = tid >> 3;                               // clustered: wave = 8 adjacent queries
    int cloud = qi >> 15, k = qi & (NPTS - 1);
    const float4* Q = cloud ? sortedB : sortedA;
    const float4* T = cloud ? sortedA : sortedB;
    const u32* s = Sall + (cloud ^ 1) * SSTR;        // other cloud's grid

    float4 q = Q[k];                                 // q.w = |q|^2/2
    int cx = cell_of(q.x), cy = cell_of(q.y), cz = cell_of(q.z);
    int x0 = max(cx - 1, 0), x1 = min(cx + 1, G - 1);
    float hb = 3.4e38f;                              // running min of h

    // center-row + 8 neighbor-row descriptors: issued early, all independent
    int cbc = (cz * G + cy) * G;
    u32 cbeg = s[cbc + x0], cend = s[cbc + x1 + 1];
    u32 rb[9], re[9];
    #pragma unroll
    for (int i = 0; i < 9; ++i) {
        int dy = (i % 3) - 1, dz = (i / 3) - 1;
        int Y = cy + dy, Z = cz + dz;
        rb[i] = 0; re[i] = 0;
        if (i != 4 && (unsigned)Y < G && (unsigned)Z < G) {
            int cb = (Z * G + Y) * G;
            rb[i] = s[cb + x0]; re[i] = s[cb + x1 + 1];
        }
    }

    auto hval = [&](float4 t) {                      // 3 fma
        return fmaf(-q.x, t.x, fmaf(-q.y, t.y, fmaf(-q.z, t.z, t.w)));
    };
    auto scan_seg = [&](u32 beg, u32 end) {
        for (u32 e = beg + sub; e < end; e += 32) {  // x4 unroll, 4 loads in flight
            u32 e1 = min(e + 8u,  (u32)NPTS - 1);
            u32 e2 = min(e + 16u, (u32)NPTS - 1);
            u32 e3 = min(e + 24u, (u32)NPTS - 1);
            float4 t0 = T[e];  float4 t1 = T[e1];
            float4 t2 = T[e2]; float4 t3 = T[e3];
            float h0 = hval(t0);
            float h1 = (e + 8u  < end) ? hval(t1) : 3.4e38f;
            float h2 = (e + 16u < end) ? hval(t2) : 3.4e38f;
            float h3 = (e + 24u < end) ? hval(t3) : 3.4e38f;
            hb = fminf(hb, fminf(fminf(h0, h1), fminf(h2, h3)));
        }
    };
    auto group_min = [&]() {
        hb = fminf(hb, __shfl_xor(hb, 1, 64));
        hb = fminf(hb, __shfl_xor(hb, 2, 64));
        hb = fminf(hb, __shfl_xor(hb, 4, 64));
    };

    // round 1: center row (contains own cell)
    scan_seg(cbeg, cend);
    group_min();

    // round 2: prune rows against post-center best, scan survivors.
    // d^2-space: mind2 < best_d2  <=>  0.5*mind2 - q.w < hb. Exact skip.
    #pragma unroll
    for (int i = 0; i < 9; ++i) {
        if (i == 4) continue;
        int dy = (i % 3) - 1, dz = (i / 3) - 1;
        int Y = cy + dy, Z = cz + dz;
        if ((unsigned)Y >= G || (unsigned)Z >= G) continue;
        float ey = dy > 0 ? cell_lo(Y) - q.y : q.y - cell_lo(Y + 1);
        float ez = dz > 0 ? cell_lo(Z) - q.z : q.z - cell_lo(Z + 1);
        if (dy == 0) ey = 0.0f;
        if (dz == 0) ez = 0.0f;
        float mind2 = fmaf(ey, ey, ez * ez);
        if (fmaf(0.5f, mind2, -q.w) < hb) scan_seg(rb[i], re[i]);
    }
    group_min();                                     // hb now group-uniform

    // straggler handoff: best_d2 > bd^2  <=>  hb > 0.5*bd^2 - q.w
    float bd = box_bound(cx, cy, cz, q, 1);
    float best;                                      // d^2 contribution
    if (hb > fmaf(0.5f * bd, bd, -q.w)) {
        if (sub == 0) {
            u32 slot = atomicAdd(strag_cnt, 1u);
            strag_list[slot] = (u32)qi;
        }
        best = 0.0f;                                 // phase 2 contributes the real value
    } else {
        best = fmaxf(fmaf(2.0f, hb, 2.0f * q.w), 0.0f);
    }

    // fused mean: each query's best replicated on its 8 lanes -> weight 1/8
    float v = best * 0.125f;
    #pragma unroll
    for (int off = 1; off < 64; off <<= 1)
        v += __shfl_xor(v, off, 64);
    __shared__ float wsum[4];
    int lane = threadIdx.x & 63, wave = threadIdx.x >> 6;
    if (lane == 0) wsum[wave] = v;
    __syncthreads();
    if (threadIdx.x == 0)
        atomicAdd(out, (wsum[0] + wsum[1] + wsum[2] + wsum[3]) * (1.0f / NPTS));
}

// ---- Phase 2: one 64-lane wave per straggler (grid-stride over the list).
// ---- box(4) with per-lane row ownership (one descriptor latency round), then
// ---- whole-cloud brute ONLY if best > bd4^2: 8-wide batched named loads +
// ---- 4 accumulators (proven: removed strag from the top-5 in R11).
__global__ __launch_bounds__(256, 8)
void query_strag(const float4* __restrict__ sortedA, const float4* __restrict__ sortedB,
                 const u32* __restrict__ Sall, const u32* __restrict__ strag_cnt,
                 const u32* __restrict__ strag_list, float* __restrict__ out) {
    u32 n = *strag_cnt;
    int lane = threadIdx.x & 63;
    u32 wid = (blockIdx.x * 256 + threadIdx.x) >> 6;
    u32 nw = (gridDim.x * 256) >> 6;

    for (u32 idx = wid; idx < n; idx += nw) {
        u32 qi = strag_list[idx];
        int cloud = qi >> 15, k = qi & (NPTS - 1);
        const float4* Q = cloud ? sortedB : sortedA;
        const float4* T = cloud ? sortedA : sortedB;
        const u32* s = Sall + (cloud ^ 1) * SSTR;

        float4 q = Q[k];
        int cx = cell_of(q.x), cy = cell_of(q.y), cz = cell_of(q.z);
        int xlo = max(cx - 4, 0), xhi = min(cx + 4, G - 1);
        float best = 3.4e38f;

        // lane-owned rows of the 9x9 (dy,dz) sheet: ri = lane and lane+64
        u32 rb0 = 0, re0 = 0, rb1 = 0, re1 = 0;
        {
            int Z = cz + lane / 9 - 4, Y = cy + lane % 9 - 4;
            if ((unsigned)Z < G && (unsigned)Y < G) {
                int cb = (Z * G + Y) * G;
                rb0 = s[cb + xlo]; re0 = s[cb + xhi + 1];
            }
        }
        if (lane < 17) {
            int ri = lane + 64;
            int Z = cz + ri / 9 - 4, Y = cy + ri % 9 - 4;
            if ((unsigned)Z < G && (unsigned)Y < G) {
                int cb = (Z * G + Y) * G;
                rb1 = s[cb + xlo]; re1 = s[cb + xhi + 1];
            }
        }
        for (u32 e = rb0; e < re0; ++e) {
            float4 t = T[e];
            float dx = q.x - t.x, dy = q.y - t.y, dz = q.z - t.z;
            best = fminf(best, fmaf(dx, dx, fmaf(dy, dy, dz * dz)));
        }
        for (u32 e = rb1; e < re1; ++e) {
            float4 t = T[e];
            float dx = q.x - t.x, dy = q.y - t.y, dz = q.z - t.z;
            best = fminf(best, fmaf(dx, dx, fmaf(dy, dy, dz * dz)));
        }
        #pragma unroll
        for (int off = 1; off < 64; off <<= 1)
            best = fminf(best, __shfl_xor(best, off, 64));

        float bd4 = box_bound(cx, cy, cz, q, 4);     // >= ~1.27 in-domain
        if (best > bd4 * bd4) {
            auto d2 = [&](float4 t) {
                float dx = q.x - t.x, dy = q.y - t.y, dz = q.z - t.z;
                return fmaf(dx, dx, fmaf(dy, dy, dz * dz));
            };
            float a0 = 3.4e38f, a1 = 3.4e38f, a2 = 3.4e38f, a3 = 3.4e38f;
            #pragma unroll 2
            for (int blk = 0; blk < NPTS / 512; ++blk) {
                u32 base = (u32)lane + (u32)blk * 512u;
                float4 t0 = T[base];       float4 t1 = T[base + 64];
                float4 t2 = T[base + 128]; float4 t3 = T[base + 192];
                float4 t4 = T[base + 256]; float4 t5 = T[base + 320];
                float4 t6 = T[base + 384]; float4 t7 = T[base + 448];
                a0 = fminf(a0, d2(t0)); a1 = fminf(a1, d2(t1));
                a2 = fminf(a2, d2(t2)); a3 = fminf(a3, d2(t3));
                a0 = fminf(a0, d2(t4)); a1 = fminf(a1, d2(t5));
                a2 = fminf(a2, d2(t6)); a3 = fminf(a3, d2(t7));
            }
            float bb = fminf(fminf(a0, a1), fminf(a2, a3));
            #pragma unroll
            for (int off = 1; off < 64; off <<= 1)
                bb = fminf(bb, __shfl_xor(bb, off, 64));
            best = fminf(best, bb);
        }

        if (lane == 0) atomicAdd(out, best * (1.0f / NPTS));
    }
}

extern "C" void kernel_launch(void* const* d_in, const int* in_sizes, int n_in,
                              void* d_out, int out_size, void* d_ws, size_t ws_size,
                              hipStream_t stream) {
    const float* pred = (const float*)d_in[0];
    const float* targ = (const float*)d_in[1];
    float* out = (float*)d_out;
    char* ws = (char*)d_ws;
    float4* sortedA = (float4*)(ws);
    float4* sortedB = (float4*)(ws + (512 << 10));
    u32* S         = (u32*)(ws + (1024 << 10));
    u32* cnt       = (u32*)(ws + (1344 << 10));   // dead after scan_k
    u32* cursor    = (u32*)(ws + (1600 << 10));
    u32* strag_cnt = (u32*)(ws + (1856 << 10));
    u32* strag_list = cnt;                        // reuse: list written after scan_k

    hipMemsetAsync(cnt, 0, 2 * NCELL * sizeof(u32), stream);
    hist_k     <<<256, 256, 0, stream>>>(pred, targ, cnt, strag_cnt, out);
    scan_k     <<<2, 1024, 0, stream>>>(cnt, S, cursor);
    scatter_k  <<<256, 256, 0, stream>>>(pred, targ, cursor, sortedA, sortedB);
    query_dense<<<2048, 256, 0, stream>>>(sortedA, sortedB, S, strag_cnt, strag_list, out);
    query_strag<<<512, 256, 0, stream>>>(sortedA, sortedB, S, strag_cnt, strag_list, out);
}

// Round 15
// 169.280 us; speedup vs baseline: 1.3038x; 1.0504x over previous
//
#include <hip/hip_runtime.h>

#define NPTS 32768
#define G 32
#define NCELL (G*G*G)          // 32768 cells per cloud
#define SSTR (NCELL + 1)
#define RANGE 4.5f
#define CELLW 0.28125f         // 9/32, exact in fp32
#define GRP 16                 // lanes per query (R11 best was 8; this halves chain)

typedef unsigned int u32;

// Workspace layout:
//  [0K)     float4 sortedA[32768]   512KB   pred, counting-sorted by cell
//  [512K)   float4 sortedB[32768]   512KB   targ, counting-sorted by cell
//  [1024K)  u32    S[2][SSTR]       257KB   exclusive scan (+terminator NPTS)
//  [1344K)  u32    cnt[2][NCELL]    256KB   histogram; REUSED as straggler list
//  [1600K)  u32    cursor[2][NCELL] 256KB   scatter cursors
//  [1856K)  u32    strag_cnt        4B     (zeroed by hist_k each replay)

__device__ __forceinline__ int cell_of(float v) {
    int c = (int)floorf((v + RANGE) * (G / (2.0f * RANGE)));
    return min(max(c, 0), G - 1);   // outliers clamp inward -> all bounds stay conservative
}
__device__ __forceinline__ float cell_lo(int i) {   // exact: i*(9/32) - 4.5
    return fmaf((float)i, CELLW, -RANGE);
}

// ---- Build stage 1: histogram, one point/thread, global atomics ----
__global__ __launch_bounds__(256)
void hist_k(const float* __restrict__ pred, const float* __restrict__ targ,
            u32* __restrict__ cnt, u32* __restrict__ strag_cnt,
            float* __restrict__ out) {
    int i = blockIdx.x * 256 + threadIdx.x;          // 0..65535
    if (i == 0) { *out = 0.0f; *strag_cnt = 0u; }    // re-zeroed every replay
    int cloud = i >> 15, k = i & (NPTS - 1);
    const float* p = cloud ? targ : pred;
    float x = p[3*k], y = p[3*k+1], z = p[3*k+2];
    int c = (cell_of(z) * G + cell_of(y)) * G + cell_of(x);
    atomicAdd(&cnt[cloud * NCELL + c], 1u);
}

// ---- Build stage 2: per-cloud exclusive scan (1 block/cloud, 32 cells/thread) ----
__global__ __launch_bounds__(1024)
void scan_k(const u32* __restrict__ cnt, u32* __restrict__ S, u32* __restrict__ cursor) {
    int cloud = blockIdx.x;
    const u32* c = cnt + cloud * NCELL;
    u32* s   = S + cloud * SSTR;
    u32* cur = cursor + cloud * NCELL;
    __shared__ u32 wt[16];
    int t = threadIdx.x, lane = t & 63, wave = t >> 6;

    u32 loc[32], run = 0;
    #pragma unroll
    for (int k = 0; k < 32; ++k) { loc[k] = run; run += c[32 * t + k]; }
    u32 inc = run;
    #pragma unroll
    for (int off = 1; off < 64; off <<= 1) {
        u32 nv = __shfl_up(inc, off, 64);
        if (lane >= off) inc += nv;
    }
    if (lane == 63) wt[wave] = inc;
    __syncthreads();
    if (t == 0) {
        u32 a = 0;
        #pragma unroll
        for (int w = 0; w < 16; ++w) { u32 v = wt[w]; wt[w] = a; a += v; }
    }
    __syncthreads();
    u32 tb = wt[wave] + (inc - run);                 // exclusive base for cell 32t
    #pragma unroll
    for (int k = 0; k < 32; ++k) {
        u32 v = tb + loc[k];
        s[32 * t + k] = v; cur[32 * t + k] = v;
    }
    if (t == 1023) s[NCELL] = NPTS;
}

// ---- Build stage 3: scatter into cell-sorted order ----
__global__ __launch_bounds__(256)
void scatter_k(const float* __restrict__ pred, const float* __restrict__ targ,
               u32* __restrict__ cursor,
               float4* __restrict__ sortedA, float4* __restrict__ sortedB) {
    int i = blockIdx.x * 256 + threadIdx.x;
    int cloud = i >> 15, k = i & (NPTS - 1);
    const float* p = cloud ? targ : pred;
    float x = p[3*k], y = p[3*k+1], z = p[3*k+2];
    int c = (cell_of(z) * G + cell_of(y)) * G + cell_of(x);
    u32 pos = atomicAdd(&cursor[cloud * NCELL + c], 1u);
    (cloud ? sortedB : sortedA)[pos] = make_float4(x, y, z, 0.0f);
}

// distance from q to the boundary of box(R); domain-edge faces skipped
// (points clamp inward -> nothing lies beyond them): bound stays conservative.
__device__ __forceinline__ float box_bound(int cx, int cy, int cz, float4 q, int R) {
    float bd = 3.4e38f;
    if (cx - R > 0)     bd = fminf(bd, q.x - cell_lo(cx - R));
    if (cx + R < G - 1) bd = fminf(bd, cell_lo(cx + R + 1) - q.x);
    if (cy - R > 0)     bd = fminf(bd, q.y - cell_lo(cy - R));
    if (cy + R < G - 1) bd = fminf(bd, cell_lo(cy + R + 1) - q.y);
    if (cz - R > 0)     bd = fminf(bd, q.z - cell_lo(cz - R));
    if (cz + R < G - 1) bd = fminf(bd, cell_lo(cz + R + 1) - q.z);
    return bd;
}

// ---- Phase 1: dense path, R11 structure (no unroll -- R12/13/14 proved any
// ---- unroll spills under the allocator's 64-VGPR occupancy choice; WRITE_SIZE
// ---- is the spill detector). Change vs R11: GRP 8->16 lanes/query, halving
// ---- the per-lane serial latency chain; live set unchanged -> no spill.
__global__ __launch_bounds__(256, 8)
void query_dense(const float4* __restrict__ sortedA, const float4* __restrict__ sortedB,
                 const u32* __restrict__ Sall, u32* __restrict__ strag_cnt,
                 u32* __restrict__ strag_list, float* __restrict__ out) {
    int tid = blockIdx.x * 256 + threadIdx.x;        // 0..1048575
    int sub = tid & (GRP - 1);
    int qi = tid / GRP;                              // clustered: wave = 4 adjacent queries
    int cloud = qi >> 15, k = qi & (NPTS - 1);
    const float4* Q = cloud ? sortedB : sortedA;
    const float4* T = cloud ? sortedA : sortedB;
    const u32* s = Sall + (cloud ^ 1) * SSTR;        // other cloud's grid

    float4 q = Q[k];
    int cx = cell_of(q.x), cy = cell_of(q.y), cz = cell_of(q.z);
    int x0 = max(cx - 1, 0), x1 = min(cx + 1, G - 1);
    float best = 3.4e38f;

    // center-row + 8 neighbor-row descriptors: issued early, all independent
    int cbc = (cz * G + cy) * G;
    u32 cbeg = s[cbc + x0], cend = s[cbc + x1 + 1];
    u32 rb[9], re[9];
    #pragma unroll
    for (int i = 0; i < 9; ++i) {
        int dy = (i % 3) - 1, dz = (i / 3) - 1;
        int Y = cy + dy, Z = cz + dz;
        rb[i] = 0; re[i] = 0;
        if (i != 4 && (unsigned)Y < G && (unsigned)Z < G) {
            int cb = (Z * G + Y) * G;
            rb[i] = s[cb + x0]; re[i] = s[cb + x1 + 1];
        }
    }

    auto scan_seg = [&](u32 beg, u32 end) {
        for (u32 e = beg + sub; e < end; e += GRP) { // 16 lanes: 256B-coalesced iters
            float4 t = T[e];
            float dx = q.x - t.x, dy = q.y - t.y, dz = q.z - t.z;
            best = fminf(best, fmaf(dx, dx, fmaf(dy, dy, dz * dz)));
        }
    };
    auto group_min = [&]() {
        best = fminf(best, __shfl_xor(best, 1, 64));
        best = fminf(best, __shfl_xor(best, 2, 64));
        best = fminf(best, __shfl_xor(best, 4, 64));
        best = fminf(best, __shfl_xor(best, 8, 64));
    };

    // round 1: center row (contains own cell)
    scan_seg(cbeg, cend);
    group_min();

    // round 2: prune rows against post-center best, scan survivors.
    // Per-lane best at prune >= final min -> skipping is exact.
    #pragma unroll
    for (int i = 0; i < 9; ++i) {
        if (i == 4) continue;
        int dy = (i % 3) - 1, dz = (i / 3) - 1;
        int Y = cy + dy, Z = cz + dz;
        if ((unsigned)Y >= G || (unsigned)Z >= G) continue;
        float ey = dy > 0 ? cell_lo(Y) - q.y : q.y - cell_lo(Y + 1);
        float ez = dz > 0 ? cell_lo(Z) - q.z : q.z - cell_lo(Z + 1);
        if (dy == 0) ey = 0.0f;
        if (dz == 0) ez = 0.0f;
        float mind2 = fmaf(ey, ey, ez * ez);
        if (mind2 < best) scan_seg(rb[i], re[i]);
    }
    group_min();                                     // best now group-uniform

    // straggler handoff (group-uniform condition)
    float bd = box_bound(cx, cy, cz, q, 1);
    if (best > bd * bd) {
        if (sub == 0) {
            u32 slot = atomicAdd(strag_cnt, 1u);
            strag_list[slot] = (u32)qi;
        }
        best = 0.0f;                                 // phase 2 contributes the real value
    }

    // fused mean: each query's best replicated on its GRP lanes -> weight 1/GRP
    float v = best * (1.0f / GRP);
    #pragma unroll
    for (int off = 1; off < 64; off <<= 1)
        v += __shfl_xor(v, off, 64);
    __shared__ float wsum[4];
    int lane = threadIdx.x & 63, wave = threadIdx.x >> 6;
    if (lane == 0) wsum[wave] = v;
    __syncthreads();
    if (threadIdx.x == 0)
        atomicAdd(out, (wsum[0] + wsum[1] + wsum[2] + wsum[3]) * (1.0f / NPTS));
}

// ---- Phase 2: one 64-lane wave per straggler (grid-stride over the list).
// ---- box(4) with per-lane row ownership (one descriptor latency round), then
// ---- whole-cloud brute ONLY if best > bd4^2: 8-wide batched named loads +
// ---- 4 accumulators (proven: removed strag from the top-5 in R11).
__global__ __launch_bounds__(256, 8)
void query_strag(const float4* __restrict__ sortedA, const float4* __restrict__ sortedB,
                 const u32* __restrict__ Sall, const u32* __restrict__ strag_cnt,
                 const u32* __restrict__ strag_list, float* __restrict__ out) {
    u32 n = *strag_cnt;
    int lane = threadIdx.x & 63;
    u32 wid = (blockIdx.x * 256 + threadIdx.x) >> 6;
    u32 nw = (gridDim.x * 256) >> 6;

    for (u32 idx = wid; idx < n; idx += nw) {
        u32 qi = strag_list[idx];
        int cloud = qi >> 15, k = qi & (NPTS - 1);
        const float4* Q = cloud ? sortedB : sortedA;
        const float4* T = cloud ? sortedA : sortedB;
        const u32* s = Sall + (cloud ^ 1) * SSTR;

        float4 q = Q[k];
        int cx = cell_of(q.x), cy = cell_of(q.y), cz = cell_of(q.z);
        int xlo = max(cx - 4, 0), xhi = min(cx + 4, G - 1);
        float best = 3.4e38f;

        // lane-owned rows of the 9x9 (dy,dz) sheet: ri = lane and lane+64
        u32 rb0 = 0, re0 = 0, rb1 = 0, re1 = 0;
        {
            int Z = cz + lane / 9 - 4, Y = cy + lane % 9 - 4;
            if ((unsigned)Z < G && (unsigned)Y < G) {
                int cb = (Z * G + Y) * G;
                rb0 = s[cb + xlo]; re0 = s[cb + xhi + 1];
            }
        }
        if (lane < 17) {
            int ri = lane + 64;
            int Z = cz + ri / 9 - 4, Y = cy + ri % 9 - 4;
            if ((unsigned)Z < G && (unsigned)Y < G) {
                int cb = (Z * G + Y) * G;
                rb1 = s[cb + xlo]; re1 = s[cb + xhi + 1];
            }
        }
        for (u32 e = rb0; e < re0; ++e) {
            float4 t = T[e];
            float dx = q.x - t.x, dy = q.y - t.y, dz = q.z - t.z;
            best = fminf(best, fmaf(dx, dx, fmaf(dy, dy, dz * dz)));
        }
        for (u32 e = rb1; e < re1; ++e) {
            float4 t = T[e];
            float dx = q.x - t.x, dy = q.y - t.y, dz = q.z - t.z;
            best = fminf(best, fmaf(dx, dx, fmaf(dy, dy, dz * dz)));
        }
        #pragma unroll
        for (int off = 1; off < 64; off <<= 1)
            best = fminf(best, __shfl_xor(best, off, 64));

        float bd4 = box_bound(cx, cy, cz, q, 4);     // >= ~1.27 in-domain
        if (best > bd4 * bd4) {
            auto d2 = [&](float4 t) {
                float dx = q.x - t.x, dy = q.y - t.y, dz = q.z - t.z;
                return fmaf(dx, dx, fmaf(dy, dy, dz * dz));
            };
            float a0 = 3.4e38f, a1 = 3.4e38f, a2 = 3.4e38f, a3 = 3.4e38f;
            #pragma unroll 2
            for (int blk = 0; blk < NPTS / 512; ++blk) {
                u32 base = (u32)lane + (u32)blk * 512u;
                float4 t0 = T[base];       float4 t1 = T[base + 64];
                float4 t2 = T[base + 128]; float4 t3 = T[base + 192];
                float4 t4 = T[base + 256]; float4 t5 = T[base + 320];
                float4 t6 = T[base + 384]; float4 t7 = T[base + 448];
                a0 = fminf(a0, d2(t0)); a1 = fminf(a1, d2(t1));
                a2 = fminf(a2, d2(t2)); a3 = fminf(a3, d2(t3));
                a0 = fminf(a0, d2(t4)); a1 = fminf(a1, d2(t5));
                a2 = fminf(a2, d2(t6)); a3 = fminf(a3, d2(t7));
            }
            float bb = fminf(fminf(a0, a1), fminf(a2, a3));
            #pragma unroll
            for (int off = 1; off < 64; off <<= 1)
                bb = fminf(bb, __shfl_xor(bb, off, 64));
            best = fminf(best, bb);
        }

        if (lane == 0) atomicAdd(out, best * (1.0f / NPTS));
    }
}

extern "C" void kernel_launch(void* const* d_in, const int* in_sizes, int n_in,
                              void* d_out, int out_size, void* d_ws, size_t ws_size,
                              hipStream_t stream) {
    const float* pred = (const float*)d_in[0];
    const float* targ = (const float*)d_in[1];
    float* out = (float*)d_out;
    char* ws = (char*)d_ws;
    float4* sortedA = (float4*)(ws);
    float4* sortedB = (float4*)(ws + (512 << 10));
    u32* S         = (u32*)(ws + (1024 << 10));
    u32* cnt       = (u32*)(ws + (1344 << 10));   // dead after scan_k
    u32* cursor    = (u32*)(ws + (1600 << 10));
    u32* strag_cnt = (u32*)(ws + (1856 << 10));
    u32* strag_list = cnt;                        // reuse: list written after scan_k

    hipMemsetAsync(cnt, 0, 2 * NCELL * sizeof(u32), stream);
    hist_k     <<<256, 256, 0, stream>>>(pred, targ, cnt, strag_cnt, out);
    scan_k     <<<2, 1024, 0, stream>>>(cnt, S, cursor);
    scatter_k  <<<256, 256, 0, stream>>>(pred, targ, cursor, sortedA, sortedB);
    query_dense<<<2 * NPTS * GRP / 256, 256, 0, stream>>>(sortedA, sortedB, S,
                                                          strag_cnt, strag_list, out);
    query_strag<<<512, 256, 0, stream>>>(sortedA, sortedB, S, strag_cnt, strag_list, out);
}

// Round 16
// 146.906 us; speedup vs baseline: 1.5024x; 1.1523x over previous
//
#include <hip/hip_runtime.h>

#define NPTS 32768
#define G 32
#define NCELL (G*G*G)          // 32768 cells per cloud
#define SSTR (NCELL + 1)
#define RANGE 4.5f
#define CELLW 0.28125f         // 9/32, exact in fp32

typedef unsigned int u32;

// Workspace layout:
//  [0K)     float4 sortedA[32768]   512KB   pred, counting-sorted by cell
//  [512K)   float4 sortedB[32768]   512KB   targ, counting-sorted by cell
//  [1024K)  u32    S[2][SSTR]       257KB   exclusive scan (+terminator NPTS)
//  [1344K)  u32    cnt[2][NCELL]    256KB   histogram; REUSED as straggler list
//  [1600K)  u32    cursor[2][NCELL] 256KB   scatter cursors
//  [1856K)  u32    strag_cnt        4B     (zeroed by hist_k each replay)

__device__ __forceinline__ int cell_of(float v) {
    int c = (int)floorf((v + RANGE) * (G / (2.0f * RANGE)));
    return min(max(c, 0), G - 1);   // outliers clamp inward -> all bounds stay conservative
}
__device__ __forceinline__ float cell_lo(int i) {   // exact: i*(9/32) - 4.5
    return fmaf((float)i, CELLW, -RANGE);
}

// ---- Build stage 1: histogram, one point/thread, global atomics ----
__global__ __launch_bounds__(256)
void hist_k(const float* __restrict__ pred, const float* __restrict__ targ,
            u32* __restrict__ cnt, u32* __restrict__ strag_cnt,
            float* __restrict__ out) {
    int i = blockIdx.x * 256 + threadIdx.x;          // 0..65535
    if (i == 0) { *out = 0.0f; *strag_cnt = 0u; }    // re-zeroed every replay
    int cloud = i >> 15, k = i & (NPTS - 1);
    const float* p = cloud ? targ : pred;
    float x = p[3*k], y = p[3*k+1], z = p[3*k+2];
    int c = (cell_of(z) * G + cell_of(y)) * G + cell_of(x);
    atomicAdd(&cnt[cloud * NCELL + c], 1u);
}

// ---- Build stage 2: per-cloud exclusive scan (1 block/cloud, 32 cells/thread) ----
__global__ __launch_bounds__(1024)
void scan_k(const u32* __restrict__ cnt, u32* __restrict__ S, u32* __restrict__ cursor) {
    int cloud = blockIdx.x;
    const u32* c = cnt + cloud * NCELL;
    u32* s   = S + cloud * SSTR;
    u32* cur = cursor + cloud * NCELL;
    __shared__ u32 wt[16];
    int t = threadIdx.x, lane = t & 63, wave = t >> 6;

    u32 loc[32], run = 0;
    #pragma unroll
    for (int k = 0; k < 32; ++k) { loc[k] = run; run += c[32 * t + k]; }
    u32 inc = run;
    #pragma unroll
    for (int off = 1; off < 64; off <<= 1) {
        u32 nv = __shfl_up(inc, off, 64);
        if (lane >= off) inc += nv;
    }
    if (lane == 63) wt[wave] = inc;
    __syncthreads();
    if (t == 0) {
        u32 a = 0;
        #pragma unroll
        for (int w = 0; w < 16; ++w) { u32 v = wt[w]; wt[w] = a; a += v; }
    }
    __syncthreads();
    u32 tb = wt[wave] + (inc - run);                 // exclusive base for cell 32t
    #pragma unroll
    for (int k = 0; k < 32; ++k) {
        u32 v = tb + loc[k];
        s[32 * t + k] = v; cur[32 * t + k] = v;
    }
    if (t == 1023) s[NCELL] = NPTS;
}

// ---- Build stage 3: scatter into cell-sorted order ----
__global__ __launch_bounds__(256)
void scatter_k(const float* __restrict__ pred, const float* __restrict__ targ,
               u32* __restrict__ cursor,
               float4* __restrict__ sortedA, float4* __restrict__ sortedB) {
    int i = blockIdx.x * 256 + threadIdx.x;
    int cloud = i >> 15, k = i & (NPTS - 1);
    const float* p = cloud ? targ : pred;
    float x = p[3*k], y = p[3*k+1], z = p[3*k+2];
    int c = (cell_of(z) * G + cell_of(y)) * G + cell_of(x);
    u32 pos = atomicAdd(&cursor[cloud * NCELL + c], 1u);
    (cloud ? sortedB : sortedA)[pos] = make_float4(x, y, z, 0.0f);
}

// distance from q to the boundary of box(R); domain-edge faces skipped
// (points clamp inward -> nothing lies beyond them): bound stays conservative.
__device__ __forceinline__ float box_bound(int cx, int cy, int cz, float4 q, int R) {
    float bd = 3.4e38f;
    if (cx - R > 0)     bd = fminf(bd, q.x - cell_lo(cx - R));
    if (cx + R < G - 1) bd = fminf(bd, cell_lo(cx + R + 1) - q.x);
    if (cy - R > 0)     bd = fminf(bd, q.y - cell_lo(cy - R));
    if (cy + R < G - 1) bd = fminf(bd, cell_lo(cy + R + 1) - q.y);
    if (cz - R > 0)     bd = fminf(bd, q.z - cell_lo(cz - R));
    if (cz + R < G - 1) bd = fminf(bd, cell_lo(cz + R + 1) - q.z);
    return bd;
}

// ---- Phase 1: dense path. EXACT R11 champion structure (GRP=8, grid 2048,
// ---- no unroll) except scan_seg: each segment is split into two halves
// ---- scanned concurrently -> 2 independent loads in flight per lane, per-lane
// ---- chain ~halved, live set +~10 regs (unlike the x4 unroll that spilled:
// ---- R12/13/14 WRITE_SIZE 322/199/59 MB scratch signatures).
__global__ __launch_bounds__(256, 8)
void query_dense(const float4* __restrict__ sortedA, const float4* __restrict__ sortedB,
                 const u32* __restrict__ Sall, u32* __restrict__ strag_cnt,
                 u32* __restrict__ strag_list, float* __restrict__ out) {
    int tid = blockIdx.x * 256 + threadIdx.x;        // 0..524287
    int sub = tid & 7;
    int qi = tid >> 3;                               // clustered: wave = 8 adjacent queries
    int cloud = qi >> 15, k = qi & (NPTS - 1);
    const float4* Q = cloud ? sortedB : sortedA;
    const float4* T = cloud ? sortedA : sortedB;
    const u32* s = Sall + (cloud ^ 1) * SSTR;        // other cloud's grid

    float4 q = Q[k];
    int cx = cell_of(q.x), cy = cell_of(q.y), cz = cell_of(q.z);
    int x0 = max(cx - 1, 0), x1 = min(cx + 1, G - 1);
    float best = 3.4e38f;

    // center-row + 8 neighbor-row descriptors: issued early, all independent
    int cbc = (cz * G + cy) * G;
    u32 cbeg = s[cbc + x0], cend = s[cbc + x1 + 1];
    u32 rb[9], re[9];
    #pragma unroll
    for (int i = 0; i < 9; ++i) {
        int dy = (i % 3) - 1, dz = (i / 3) - 1;
        int Y = cy + dy, Z = cz + dz;
        rb[i] = 0; re[i] = 0;
        if (i != 4 && (unsigned)Y < G && (unsigned)Z < G) {
            int cb = (Z * G + Y) * G;
            rb[i] = s[cb + x0]; re[i] = s[cb + x1 + 1];
        }
    }

    auto d2f = [&](float4 t) {
        float dx = q.x - t.x, dy = q.y - t.y, dz = q.z - t.z;
        return fmaf(dx, dx, fmaf(dy, dy, dz * dz));
    };
    // split-scan: halves A=[beg,mid), B=[mid,end) walked concurrently.
    // Coverage: o in [0,half) stride 8 per lane; A index beg+o < mid always;
    // B index mid+o covers [mid,mid+half) >= [mid,end), tail INF-masked.
    auto scan_seg = [&](u32 beg, u32 end) {
        if (beg >= end) return;
        u32 half = (end - beg + 1) >> 1;
        u32 mid = beg + half;
        for (u32 o = sub; o < half; o += 8) {
            u32 ea = beg + o;
            u32 eb = min(mid + o, (u32)(NPTS - 1));
            float4 ta = T[ea];                       // 2 independent loads in flight
            float4 tb = T[eb];
            float da = d2f(ta);
            float db = (mid + o < end) ? d2f(tb) : 3.4e38f;
            best = fminf(best, fminf(da, db));
        }
    };
    auto group_min = [&]() {
        best = fminf(best, __shfl_xor(best, 1, 64));
        best = fminf(best, __shfl_xor(best, 2, 64));
        best = fminf(best, __shfl_xor(best, 4, 64));
    };

    // round 1: center row (contains own cell)
    scan_seg(cbeg, cend);
    group_min();

    // round 2: prune rows against post-center best, scan survivors.
    // Per-lane best at prune >= final min -> skipping is exact.
    #pragma unroll
    for (int i = 0; i < 9; ++i) {
        if (i == 4) continue;
        int dy = (i % 3) - 1, dz = (i / 3) - 1;
        int Y = cy + dy, Z = cz + dz;
        if ((unsigned)Y >= G || (unsigned)Z >= G) continue;
        float ey = dy > 0 ? cell_lo(Y) - q.y : q.y - cell_lo(Y + 1);
        float ez = dz > 0 ? cell_lo(Z) - q.z : q.z - cell_lo(Z + 1);
        if (dy == 0) ey = 0.0f;
        if (dz == 0) ez = 0.0f;
        float mind2 = fmaf(ey, ey, ez * ez);
        if (mind2 < best) scan_seg(rb[i], re[i]);
    }
    group_min();                                     // best now group-uniform

    // straggler handoff (group-uniform condition)
    float bd = box_bound(cx, cy, cz, q, 1);
    if (best > bd * bd) {
        if (sub == 0) {
            u32 slot = atomicAdd(strag_cnt, 1u);
            strag_list[slot] = (u32)qi;
        }
        best = 0.0f;                                 // phase 2 contributes the real value
    }

    // fused mean: each query's best replicated on its 8 lanes -> weight 1/8
    float v = best * 0.125f;
    #pragma unroll
    for (int off = 1; off < 64; off <<= 1)
        v += __shfl_xor(v, off, 64);
    __shared__ float wsum[4];
    int lane = threadIdx.x & 63, wave = threadIdx.x >> 6;
    if (lane == 0) wsum[wave] = v;
    __syncthreads();
    if (threadIdx.x == 0)
        atomicAdd(out, (wsum[0] + wsum[1] + wsum[2] + wsum[3]) * (1.0f / NPTS));
}

// ---- Phase 2: one 64-lane wave per straggler (grid-stride over the list).
// ---- box(4) with per-lane row ownership (one descriptor latency round), then
// ---- whole-cloud brute ONLY if best > bd4^2: 8-wide batched named loads +
// ---- 4 accumulators (proven: removed strag from the top-5 in R11).
__global__ __launch_bounds__(256, 8)
void query_strag(const float4* __restrict__ sortedA, const float4* __restrict__ sortedB,
                 const u32* __restrict__ Sall, const u32* __restrict__ strag_cnt,
                 const u32* __restrict__ strag_list, float* __restrict__ out) {
    u32 n = *strag_cnt;
    int lane = threadIdx.x & 63;
    u32 wid = (blockIdx.x * 256 + threadIdx.x) >> 6;
    u32 nw = (gridDim.x * 256) >> 6;

    for (u32 idx = wid; idx < n; idx += nw) {
        u32 qi = strag_list[idx];
        int cloud = qi >> 15, k = qi & (NPTS - 1);
        const float4* Q = cloud ? sortedB : sortedA;
        const float4* T = cloud ? sortedA : sortedB;
        const u32* s = Sall + (cloud ^ 1) * SSTR;

        float4 q = Q[k];
        int cx = cell_of(q.x), cy = cell_of(q.y), cz = cell_of(q.z);
        int xlo = max(cx - 4, 0), xhi = min(cx + 4, G - 1);
        float best = 3.4e38f;

        // lane-owned rows of the 9x9 (dy,dz) sheet: ri = lane and lane+64
        u32 rb0 = 0, re0 = 0, rb1 = 0, re1 = 0;
        {
            int Z = cz + lane / 9 - 4, Y = cy + lane % 9 - 4;
            if ((unsigned)Z < G && (unsigned)Y < G) {
                int cb = (Z * G + Y) * G;
                rb0 = s[cb + xlo]; re0 = s[cb + xhi + 1];
            }
        }
        if (lane < 17) {
            int ri = lane + 64;
            int Z = cz + ri / 9 - 4, Y = cy + ri % 9 - 4;
            if ((unsigned)Z < G && (unsigned)Y < G) {
                int cb = (Z * G + Y) * G;
                rb1 = s[cb + xlo]; re1 = s[cb + xhi + 1];
            }
        }
        for (u32 e = rb0; e < re0; ++e) {
            float4 t = T[e];
            float dx = q.x - t.x, dy = q.y - t.y, dz = q.z - t.z;
            best = fminf(best, fmaf(dx, dx, fmaf(dy, dy, dz * dz)));
        }
        for (u32 e = rb1; e < re1; ++e) {
            float4 t = T[e];
            float dx = q.x - t.x, dy = q.y - t.y, dz = q.z - t.z;
            best = fminf(best, fmaf(dx, dx, fmaf(dy, dy, dz * dz)));
        }
        #pragma unroll
        for (int off = 1; off < 64; off <<= 1)
            best = fminf(best, __shfl_xor(best, off, 64));

        float bd4 = box_bound(cx, cy, cz, q, 4);     // >= ~1.27 in-domain
        if (best > bd4 * bd4) {
            auto d2 = [&](float4 t) {
                float dx = q.x - t.x, dy = q.y - t.y, dz = q.z - t.z;
                return fmaf(dx, dx, fmaf(dy, dy, dz * dz));
            };
            float a0 = 3.4e38f, a1 = 3.4e38f, a2 = 3.4e38f, a3 = 3.4e38f;
            #pragma unroll 2
            for (int blk = 0; blk < NPTS / 512; ++blk) {
                u32 base = (u32)lane + (u32)blk * 512u;
                float4 t0 = T[base];       float4 t1 = T[base + 64];
                float4 t2 = T[base + 128]; float4 t3 = T[base + 192];
                float4 t4 = T[base + 256]; float4 t5 = T[base + 320];
                float4 t6 = T[base + 384]; float4 t7 = T[base + 448];
                a0 = fminf(a0, d2(t0)); a1 = fminf(a1, d2(t1));
                a2 = fminf(a2, d2(t2)); a3 = fminf(a3, d2(t3));
                a0 = fminf(a0, d2(t4)); a1 = fminf(a1, d2(t5));
                a2 = fminf(a2, d2(t6)); a3 = fminf(a3, d2(t7));
            }
            float bb = fminf(fminf(a0, a1), fminf(a2, a3));
            #pragma unroll
            for (int off = 1; off < 64; off <<= 1)
                bb = fminf(bb, __shfl_xor(bb, off, 64));
            best = fminf(best, bb);
        }

        if (lane == 0) atomicAdd(out, best * (1.0f / NPTS));
    }
}

extern "C" void kernel_launch(void* const* d_in, const int* in_sizes, int n_in,
                              void* d_out, int out_size, void* d_ws, size_t ws_size,
                              hipStream_t stream) {
    const float* pred = (const float*)d_in[0];
    const float* targ = (const float*)d_in[1];
    float* out = (float*)d_out;
    char* ws = (char*)d_ws;
    float4* sortedA = (float4*)(ws);
    float4* sortedB = (float4*)(ws + (512 << 10));
    u32* S         = (u32*)(ws + (1024 << 10));
    u32* cnt       = (u32*)(ws + (1344 << 10));   // dead after scan_k
    u32* cursor    = (u32*)(ws + (1600 << 10));
    u32* strag_cnt = (u32*)(ws + (1856 << 10));
    u32* strag_list = cnt;                        // reuse: list written after scan_k

    hipMemsetAsync(cnt, 0, 2 * NCELL * sizeof(u32), stream);
    hist_k     <<<256, 256, 0, stream>>>(pred, targ, cnt, strag_cnt, out);
    scan_k     <<<2, 1024, 0, stream>>>(cnt, S, cursor);
    scatter_k  <<<256, 256, 0, stream>>>(pred, targ, cursor, sortedA, sortedB);
    query_dense<<<2048, 256, 0, stream>>>(sortedA, sortedB, S, strag_cnt, strag_list, out);
    query_strag<<<512, 256, 0, stream>>>(sortedA, sortedB, S, strag_cnt, strag_list, out);
}